// Round 2
// baseline (25.214 us; speedup 1.0000x reference)
//
#include <hip/hip_runtime.h>
#include <math.h>

#define BLOCK 256
#define NP 16          // param sets
#define NANG 28        // 12 rot + 4 ising + 12 entangle (c,s) pairs per p

typedef float v2f __attribute__((ext_vector_type(2)));  // (re, im) -> v_pk_*_f32

// multiply by -i: -i*(r + i q) = q - i r
__device__ __forceinline__ v2f jneg(v2f a) { return (v2f){a.y, -a.x}; }

// ---- gates: fully unrolled, compile-time masks => all indices constant ----

template<int BP>
__device__ __forceinline__ void gate_ry(v2f a[16], float c, float s) {
    constexpr int M = 1 << BP;
#pragma unroll
    for (int i = 0; i < 16; ++i) {
        if (i & M) continue;
        const int j = i | M;
        v2f a0 = a[i], a1 = a[j];
        a[i] = c * a0 - s * a1;
        a[j] = s * a0 + c * a1;
    }
}

template<int BP>
__device__ __forceinline__ void gate_rx(v2f a[16], float c, float s) {
    constexpr int M = 1 << BP;
#pragma unroll
    for (int i = 0; i < 16; ++i) {
        if (i & M) continue;
        const int j = i | M;
        v2f a0 = a[i], a1 = a[j];
        a[i] = c * a0 + s * jneg(a1);   // RX = c I - i s X
        a[j] = c * a1 + s * jneg(a0);
    }
}

template<int BP1, int BP2>
__device__ __forceinline__ void gate_xx(v2f a[16], float c, float s) {
    constexpr int M = (1 << BP1) | (1 << BP2);
#pragma unroll
    for (int i = 0; i < 16; ++i) {
        const int j = i ^ M;
        if (j < i) continue;
        v2f a0 = a[i], a1 = a[j];
        a[i] = c * a0 + s * jneg(a1);   // XX rotation = c I - i s (XX)
        a[j] = c * a1 + s * jneg(a0);
    }
}

template<int CBP, int TBP>
__device__ __forceinline__ void gate_crx(v2f a[16], float c, float s) {
    constexpr int CM = 1 << CBP, TM = 1 << TBP;
#pragma unroll
    for (int i = 0; i < 16; ++i) {
        if (!(i & CM) || (i & TM)) continue;  // control=1, target=0
        const int j = i | TM;
        v2f a0 = a[i], a1 = a[j];
        a[i] = c * a0 + s * jneg(a1);
        a[j] = c * a1 + s * jneg(a0);
    }
}

__global__ __launch_bounds__(BLOCK) void qnn_kernel(
    const float* __restrict__ x,
    const float* __restrict__ p_rotation,
    const float* __restrict__ p_ising,
    const float* __restrict__ p_entangle,
    float* __restrict__ out, int B)
{
    // transposed table: cs[k*NP + p] -> 16 lanes read 16 consecutive float2
    // (spans all 32 banks, conflict-free; 4 replicas broadcast)
    __shared__ v2f cs[NANG * NP];
    const int tid = threadIdx.x;
    for (int i = tid; i < NP * NANG; i += BLOCK) {
        const int k = i >> 4, p = i & 15;
        float ang;
        if (k < 12)       ang = p_rotation[p * 12 + k];
        else if (k < 16)  ang = p_ising[p * 4 + (k - 12)];
        else              ang = p_entangle[p * 12 + (k - 16)];
        float s, c;
        __sincosf(0.5f * ang, &s, &c);
        cs[i] = (v2f){c, s};
    }
    __syncthreads();

    const int gid = blockIdx.x * BLOCK + tid;
    const int p = gid & 15;
    const int b = gid >> 4;
    if (b >= B) return;

    // ---- init: normalized RX angle embedding, product state ----
    const float4 xv = reinterpret_cast<const float4*>(x)[b];
    const float inv = rsqrtf(xv.x*xv.x + xv.y*xv.y + xv.z*xv.z + xv.w*xv.w);
    float cw[4], sw[4];
    __sincosf(0.5f * xv.x * inv, &sw[0], &cw[0]);
    __sincosf(0.5f * xv.y * inv, &sw[1], &cw[1]);
    __sincosf(0.5f * xv.z * inv, &sw[2], &cw[2]);
    __sincosf(0.5f * xv.w * inv, &sw[3], &cw[3]);

    // amp(idx) = prod_w (bit_w ? -i sin : cos); bit3 = wire0 ... bit0 = wire3
    v2f a[16];
#pragma unroll
    for (int idx = 0; idx < 16; ++idx) {
        float m = ((idx & 8) ? sw[0] : cw[0]) * ((idx & 4) ? sw[1] : cw[1])
                * ((idx & 2) ? sw[2] : cw[2]) * ((idx & 1) ? sw[3] : cw[3]);
        const int k = __popc(idx) & 3;  // (-i)^k phase
        a[idx] = (k == 0) ? (v2f){ m, 0.0f}
               : (k == 1) ? (v2f){ 0.0f, -m}
               : (k == 2) ? (v2f){-m, 0.0f}
                          : (v2f){ 0.0f,  m};
    }

    v2f t;
#define COEF(k) t = cs[(k) * NP + p]
    // layer 1: RY on wires 0..3 (bit 3-w)
    COEF(0);  gate_ry<3>(a, t.x, t.y);
    COEF(1);  gate_ry<2>(a, t.x, t.y);
    COEF(2);  gate_ry<1>(a, t.x, t.y);
    COEF(3);  gate_ry<0>(a, t.x, t.y);
    // IsingXX (0,1), (2,3)
    COEF(12); gate_xx<3,2>(a, t.x, t.y);
    COEF(13); gate_xx<1,0>(a, t.x, t.y);
    // layer 2: RX
    COEF(4);  gate_rx<3>(a, t.x, t.y);
    COEF(5);  gate_rx<2>(a, t.x, t.y);
    COEF(6);  gate_rx<1>(a, t.x, t.y);
    COEF(7);  gate_rx<0>(a, t.x, t.y);
    // IsingXX (1,2), (3,0)
    COEF(14); gate_xx<2,1>(a, t.x, t.y);
    COEF(15); gate_xx<0,3>(a, t.x, t.y);
    // layer 3: RY
    COEF(8);  gate_ry<3>(a, t.x, t.y);
    COEF(9);  gate_ry<2>(a, t.x, t.y);
    COEF(10); gate_ry<1>(a, t.x, t.y);
    COEF(11); gate_ry<0>(a, t.x, t.y);
    // CRX entangling layer: (control, target) bits = 3 - wire
    COEF(16); gate_crx<3,2>(a, t.x, t.y);  // (0,1)
    COEF(17); gate_crx<3,1>(a, t.x, t.y);  // (0,2)
    COEF(18); gate_crx<3,0>(a, t.x, t.y);  // (0,3)
    COEF(19); gate_crx<2,3>(a, t.x, t.y);  // (1,0)
    COEF(20); gate_crx<2,1>(a, t.x, t.y);  // (1,2)
    COEF(21); gate_crx<2,0>(a, t.x, t.y);  // (1,3)
    COEF(22); gate_crx<1,3>(a, t.x, t.y);  // (2,0)
    COEF(23); gate_crx<1,2>(a, t.x, t.y);  // (2,1)
    COEF(24); gate_crx<1,0>(a, t.x, t.y);  // (2,3)
    COEF(25); gate_crx<0,3>(a, t.x, t.y);  // (3,0)
    COEF(26); gate_crx<0,2>(a, t.x, t.y);  // (3,1)
    COEF(27); gate_crx<0,1>(a, t.x, t.y);  // (3,2)
#undef COEF

    // ---- measurements: Z on wire0 (bit3) and wire2 (bit1) ----
    float z0 = 0.0f, z2 = 0.0f;
#pragma unroll
    for (int idx = 0; idx < 16; ++idx) {
        const float pr = a[idx].x * a[idx].x + a[idx].y * a[idx].y;
        z0 += (idx & 8) ? -pr : pr;
        z2 += (idx & 2) ? -pr : pr;
    }
    out[b * 32 + p]      = z0;
    out[b * 32 + 16 + p] = z2;
}

extern "C" void kernel_launch(void* const* d_in, const int* in_sizes, int n_in,
                              void* d_out, int out_size, void* d_ws, size_t ws_size,
                              hipStream_t stream) {
    const float* x  = (const float*)d_in[0];
    const float* pr = (const float*)d_in[1];
    const float* pi = (const float*)d_in[2];
    const float* pe = (const float*)d_in[3];
    float* out = (float*)d_out;
    const int B = in_sizes[0] / 4;
    const int total = B * NP;
    const int grid = (total + BLOCK - 1) / BLOCK;
    qnn_kernel<<<grid, BLOCK, 0, stream>>>(x, pr, pi, pe, out, B);
}

// Round 3
// 21.819 us; speedup vs baseline: 1.1556x; 1.1556x over previous
//
#include <hip/hip_runtime.h>
#include <math.h>

#define NP 16
#define NANG 28

// ================= setup: build V_p = U_p * D, lane = amplitude index ========
// One block per p. 256 threads = 16 groups of 16 lanes; group = column k of V,
// lane-within-group = amplitude index. Gates act as paired-amplitude rotations
// -> partner amp via __shfl_xor within the 16-lane group. No LDS state, no
// barriers in the gate sequence.

template<int M>
__device__ __forceinline__ void g_ry(float& re, float& im, int idx, float c, float s) {
    float rep = __shfl_xor(re, M, 16);
    float imp = __shfl_xor(im, M, 16);
    float sgn = (idx & M) ? s : -s;       // new0 = c a0 - s a1 ; new1 = s a0 + c a1
    re = fmaf(c, re, sgn * rep);
    im = fmaf(c, im, sgn * imp);
}

template<int M>  // RX and IsingXX: a' = c a - i s a_partner  (uniform both halves)
__device__ __forceinline__ void g_rxlike(float& re, float& im, float c, float s) {
    float rep = __shfl_xor(re, M, 16);
    float imp = __shfl_xor(im, M, 16);
    re = fmaf(c, re,  s * imp);
    im = fmaf(c, im, -s * rep);
}

template<int CM, int TM>
__device__ __forceinline__ void g_crx(float& re, float& im, int idx, float c, float s) {
    float rep = __shfl_xor(re, TM, 16);
    float imp = __shfl_xor(im, TM, 16);
    float nre = fmaf(c, re,  s * imp);
    float nim = fmaf(c, im, -s * rep);
    re = (idx & CM) ? nre : re;           // control=1 rows get RX, else identity
    im = (idx & CM) ? nim : im;
}

__global__ __launch_bounds__(256) void build_V(
    const float* __restrict__ p_rotation,
    const float* __restrict__ p_ising,
    const float* __restrict__ p_entangle,
    float* __restrict__ Vr, float* __restrict__ Vi)
{
    __shared__ float2 cs[NANG];
    const int p = blockIdx.x;
    const int tid = threadIdx.x;
    if (tid < NANG) {
        float ang;
        if (tid < 12)       ang = p_rotation[p * 12 + tid];
        else if (tid < 16)  ang = p_ising[p * 4 + (tid - 12)];
        else                ang = p_entangle[p * 12 + (tid - 16)];
        float s, c;
        __sincosf(0.5f * ang, &s, &c);
        cs[tid] = make_float2(c, s);
    }
    __syncthreads();

    const int idx = tid & 15;   // amplitude index
    const int col = tid >> 4;   // column k of V = U*D
    // init: a = (-i)^popc(col) * delta(idx,col)
    const int ph = __popc(col) & 3;
    const float dre = (ph == 0) ? 1.f : (ph == 2 ? -1.f : 0.f);
    const float dim = (ph == 1) ? -1.f : (ph == 3 ? 1.f : 0.f);
    float re = (idx == col) ? dre : 0.f;
    float im = (idx == col) ? dim : 0.f;

    float2 t;
    // layer 1: RY wires 0..3 (bit 3-w)
    t = cs[0];  g_ry<8>(re, im, idx, t.x, t.y);
    t = cs[1];  g_ry<4>(re, im, idx, t.x, t.y);
    t = cs[2];  g_ry<2>(re, im, idx, t.x, t.y);
    t = cs[3];  g_ry<1>(re, im, idx, t.x, t.y);
    // IsingXX (0,1), (2,3)
    t = cs[12]; g_rxlike<12>(re, im, t.x, t.y);
    t = cs[13]; g_rxlike<3>(re, im, t.x, t.y);
    // layer 2: RX
    t = cs[4];  g_rxlike<8>(re, im, t.x, t.y);
    t = cs[5];  g_rxlike<4>(re, im, t.x, t.y);
    t = cs[6];  g_rxlike<2>(re, im, t.x, t.y);
    t = cs[7];  g_rxlike<1>(re, im, t.x, t.y);
    // IsingXX (1,2), (3,0)
    t = cs[14]; g_rxlike<6>(re, im, t.x, t.y);
    t = cs[15]; g_rxlike<9>(re, im, t.x, t.y);
    // layer 3: RY
    t = cs[8];  g_ry<8>(re, im, idx, t.x, t.y);
    t = cs[9];  g_ry<4>(re, im, idx, t.x, t.y);
    t = cs[10]; g_ry<2>(re, im, idx, t.x, t.y);
    t = cs[11]; g_ry<1>(re, im, idx, t.x, t.y);
    // CRX layer, (control_mask, target_mask)
    t = cs[16]; g_crx<8,4>(re, im, idx, t.x, t.y);  // (0,1)
    t = cs[17]; g_crx<8,2>(re, im, idx, t.x, t.y);  // (0,2)
    t = cs[18]; g_crx<8,1>(re, im, idx, t.x, t.y);  // (0,3)
    t = cs[19]; g_crx<4,8>(re, im, idx, t.x, t.y);  // (1,0)
    t = cs[20]; g_crx<4,2>(re, im, idx, t.x, t.y);  // (1,2)
    t = cs[21]; g_crx<4,1>(re, im, idx, t.x, t.y);  // (1,3)
    t = cs[22]; g_crx<2,8>(re, im, idx, t.x, t.y);  // (2,0)
    t = cs[23]; g_crx<2,4>(re, im, idx, t.x, t.y);  // (2,1)
    t = cs[24]; g_crx<2,1>(re, im, idx, t.x, t.y);  // (2,3)
    t = cs[25]; g_crx<1,8>(re, im, idx, t.x, t.y);  // (3,0)
    t = cs[26]; g_crx<1,4>(re, im, idx, t.x, t.y);  // (3,1)
    t = cs[27]; g_crx<1,2>(re, im, idx, t.x, t.y);  // (3,2)

    Vr[(p * 16 + idx) * 16 + col] = re;
    Vi[(p * 16 + idx) * 16 + col] = im;
}

// ================= main: out = signed |V_p m_b|^2 sums =======================
// p = blockIdx.y -> V addresses are wave-uniform -> scalar (SMEM) loads,
// SGPR-operand FMAs, no LDS, no per-lane V traffic.

__global__ __launch_bounds__(256) void qnn_main(
    const float* __restrict__ x,
    const float* __restrict__ Vr,
    const float* __restrict__ Vi,
    float* __restrict__ out, int B)
{
    const int p = blockIdx.y;
    const int b = blockIdx.x * 256 + threadIdx.x;
    if (b >= B) return;

    const float4 xv = reinterpret_cast<const float4*>(x)[b];
    const float inv = rsqrtf(xv.x*xv.x + xv.y*xv.y + xv.z*xv.z + xv.w*xv.w);
    float c0,s0,c1,s1,c2,s2,c3,s3;
    __sincosf(0.5f * xv.x * inv, &s0, &c0);
    __sincosf(0.5f * xv.y * inv, &s1, &c1);
    __sincosf(0.5f * xv.z * inv, &s2, &c2);
    __sincosf(0.5f * xv.w * inv, &s3, &c3);

    // m[idx] = (bit3?s0:c0)(bit2?s1:c1)(bit1?s2:c2)(bit0?s3:c3)
    float t01[4] = { c0*c1, c0*s1, s0*c1, s0*s1 };
    float t23[4] = { c2*c3, c2*s3, s2*c3, s2*s3 };
    float m[16];
#pragma unroll
    for (int i = 0; i < 16; ++i) m[i] = t01[i >> 2] * t23[i & 3];

    const float* __restrict__ vr = Vr + p * 256;
    const float* __restrict__ vi = Vi + p * 256;
    float z0 = 0.f, z2 = 0.f;
#pragma unroll
    for (int idx = 0; idx < 16; ++idx) {
        float tr = 0.f, ti = 0.f;
#pragma unroll
        for (int k = 0; k < 16; ++k) {
            tr = fmaf(vr[idx * 16 + k], m[k], tr);
            ti = fmaf(vi[idx * 16 + k], m[k], ti);
        }
        const float prob = tr * tr + ti * ti;
        z0 += (idx & 8) ? -prob : prob;
        z2 += (idx & 2) ? -prob : prob;
    }
    out[b * 32 + p]      = z0;
    out[b * 32 + 16 + p] = z2;
}

extern "C" void kernel_launch(void* const* d_in, const int* in_sizes, int n_in,
                              void* d_out, int out_size, void* d_ws, size_t ws_size,
                              hipStream_t stream) {
    const float* x  = (const float*)d_in[0];
    const float* pr = (const float*)d_in[1];
    const float* pi = (const float*)d_in[2];
    const float* pe = (const float*)d_in[3];
    float* out = (float*)d_out;
    const int B = in_sizes[0] / 4;

    float* Vr = (float*)d_ws;          // 16*16*16 floats = 16 KB
    float* Vi = Vr + NP * 256;         // +16 KB (ws_size must be >= 32 KB)

    build_V<<<NP, 256, 0, stream>>>(pr, pi, pe, Vr, Vi);
    qnn_main<<<dim3((B + 255) / 256, NP), 256, 0, stream>>>(x, Vr, Vi, out, B);
}

// Round 4
// 17.827 us; speedup vs baseline: 1.4144x; 1.2239x over previous
//
#include <hip/hip_runtime.h>
#include <math.h>

#define NP 16
#define NANG 28
#define NPAIR 136   // 16*17/2 upper-triangle pairs
#define NQUAD 68    // NPAIR/2 float4 groups

// ================= build V_p = U_p * D via lane-shuffle evolution ============

template<int M>
__device__ __forceinline__ void g_ry(float& re, float& im, int idx, float c, float s) {
    float rep = __shfl_xor(re, M, 16);
    float imp = __shfl_xor(im, M, 16);
    float sgn = (idx & M) ? s : -s;
    re = fmaf(c, re, sgn * rep);
    im = fmaf(c, im, sgn * imp);
}

template<int M>  // RX / IsingXX: a' = c a - i s a_partner
__device__ __forceinline__ void g_rxlike(float& re, float& im, float c, float s) {
    float rep = __shfl_xor(re, M, 16);
    float imp = __shfl_xor(im, M, 16);
    re = fmaf(c, re,  s * imp);
    im = fmaf(c, im, -s * rep);
}

template<int CM, int TM>
__device__ __forceinline__ void g_crx(float& re, float& im, int idx, float c, float s) {
    float rep = __shfl_xor(re, TM, 16);
    float imp = __shfl_xor(im, TM, 16);
    float nre = fmaf(c, re,  s * imp);
    float nim = fmaf(c, im, -s * rep);
    re = (idx & CM) ? nre : re;
    im = (idx & CM) ? nim : im;
}

// One block per p: evolve V, then reduce to quadratic forms
//   W0[k,k'] = sum_idx s0(idx)(Vr[idx,k]Vr[idx,k'] + Vi[idx,k]Vi[idx,k'])
// stored as float2{w0,w2} at index ((pair>>1)*16+p)*2 + (pair&1)
// (= float4 lanes for the main kernel's b128 reads), off-diag pre-doubled.
__global__ __launch_bounds__(256) void build_W(
    const float* __restrict__ p_rotation,
    const float* __restrict__ p_ising,
    const float* __restrict__ p_entangle,
    float2* __restrict__ WT)
{
    __shared__ float2 cs[NANG];
    __shared__ float2 V[256];   // V[idx*16+col] = {re,im}
    const int p = blockIdx.x;
    const int tid = threadIdx.x;
    if (tid < NANG) {
        float ang;
        if (tid < 12)       ang = p_rotation[p * 12 + tid];
        else if (tid < 16)  ang = p_ising[p * 4 + (tid - 12)];
        else                ang = p_entangle[p * 12 + (tid - 16)];
        float s, c;
        __sincosf(0.5f * ang, &s, &c);
        cs[tid] = make_float2(c, s);
    }
    __syncthreads();

    const int idx = tid & 15;   // amplitude (row)
    const int col = tid >> 4;   // column of V = U*D
    const int ph = __popc(col) & 3;     // (-i)^popc phase of D
    const float dre = (ph == 0) ? 1.f : (ph == 2 ? -1.f : 0.f);
    const float dim = (ph == 1) ? -1.f : (ph == 3 ? 1.f : 0.f);
    float re = (idx == col) ? dre : 0.f;
    float im = (idx == col) ? dim : 0.f;

    float2 t;
    t = cs[0];  g_ry<8>(re, im, idx, t.x, t.y);
    t = cs[1];  g_ry<4>(re, im, idx, t.x, t.y);
    t = cs[2];  g_ry<2>(re, im, idx, t.x, t.y);
    t = cs[3];  g_ry<1>(re, im, idx, t.x, t.y);
    t = cs[12]; g_rxlike<12>(re, im, t.x, t.y);
    t = cs[13]; g_rxlike<3>(re, im, t.x, t.y);
    t = cs[4];  g_rxlike<8>(re, im, t.x, t.y);
    t = cs[5];  g_rxlike<4>(re, im, t.x, t.y);
    t = cs[6];  g_rxlike<2>(re, im, t.x, t.y);
    t = cs[7];  g_rxlike<1>(re, im, t.x, t.y);
    t = cs[14]; g_rxlike<6>(re, im, t.x, t.y);
    t = cs[15]; g_rxlike<9>(re, im, t.x, t.y);
    t = cs[8];  g_ry<8>(re, im, idx, t.x, t.y);
    t = cs[9];  g_ry<4>(re, im, idx, t.x, t.y);
    t = cs[10]; g_ry<2>(re, im, idx, t.x, t.y);
    t = cs[11]; g_ry<1>(re, im, idx, t.x, t.y);
    t = cs[16]; g_crx<8,4>(re, im, idx, t.x, t.y);
    t = cs[17]; g_crx<8,2>(re, im, idx, t.x, t.y);
    t = cs[18]; g_crx<8,1>(re, im, idx, t.x, t.y);
    t = cs[19]; g_crx<4,8>(re, im, idx, t.x, t.y);
    t = cs[20]; g_crx<4,2>(re, im, idx, t.x, t.y);
    t = cs[21]; g_crx<4,1>(re, im, idx, t.x, t.y);
    t = cs[22]; g_crx<2,8>(re, im, idx, t.x, t.y);
    t = cs[23]; g_crx<2,4>(re, im, idx, t.x, t.y);
    t = cs[24]; g_crx<2,1>(re, im, idx, t.x, t.y);
    t = cs[25]; g_crx<1,8>(re, im, idx, t.x, t.y);
    t = cs[26]; g_crx<1,4>(re, im, idx, t.x, t.y);
    t = cs[27]; g_crx<1,2>(re, im, idx, t.x, t.y);

    V[idx * 16 + col] = make_float2(re, im);
    __syncthreads();

    if (tid < NPAIR) {
        int i = 0, j = tid;                 // decode pair index -> (i<=j)
        while (j >= 16 - i) { j -= 16 - i; ++i; }
        j += i;
        float w0 = 0.f, w2 = 0.f;
        for (int q = 0; q < 16; ++q) {
            float2 a = V[q * 16 + i], b = V[q * 16 + j];
            float d = fmaf(a.x, b.x, a.y * b.y);
            w0 += (q & 8) ? -d : d;
            w2 += (q & 2) ? -d : d;
        }
        if (i != j) { w0 *= 2.f; w2 *= 2.f; }
        WT[((tid >> 1) * 16 + p) * 2 + (tid & 1)] = make_float2(w0, w2);
    }
}

// ================= main: z = m^T W m, thread = (b, p=tid&15) =================

__global__ __launch_bounds__(256) void qnn_main(
    const float* __restrict__ x,
    const float4* __restrict__ WT4,
    float* __restrict__ out, int B)
{
    __shared__ float4 W[NQUAD * 16];    // 17408 B
    const int tid = threadIdx.x;
    for (int i = tid; i < NQUAD * 16; i += 256) W[i] = WT4[i];
    __syncthreads();

    const int gid = blockIdx.x * 256 + tid;
    const int p = tid & 15;
    const int b = gid >> 4;
    if (b >= B) return;

    const float4 xv = reinterpret_cast<const float4*>(x)[b];
    const float inv = rsqrtf(xv.x*xv.x + xv.y*xv.y + xv.z*xv.z + xv.w*xv.w);
    float c0,s0,c1,s1,c2,s2,c3,s3;
    __sincosf(0.5f * xv.x * inv, &s0, &c0);
    __sincosf(0.5f * xv.y * inv, &s1, &c1);
    __sincosf(0.5f * xv.z * inv, &s2, &c2);
    __sincosf(0.5f * xv.w * inv, &s3, &c3);

    float t01[4] = { c0*c1, c0*s1, s0*c1, s0*s1 };
    float t23[4] = { c2*c3, c2*s3, s2*c3, s2*s3 };
    float m[16];
#pragma unroll
    for (int i = 0; i < 16; ++i) m[i] = t01[i >> 2] * t23[i & 3];

    float z0 = 0.f, z2 = 0.f;
    float4 f4 = make_float4(0.f, 0.f, 0.f, 0.f);
#pragma unroll
    for (int i = 0; i < 16; ++i) {
#pragma unroll
        for (int j = i; j < 16; ++j) {
            const int k = i * 16 - (i * (i - 1)) / 2 + (j - i);   // 0..135
            if ((k & 1) == 0) f4 = W[(k >> 1) * 16 + p];
            const float mm = m[i] * m[j];
            z0 = fmaf((k & 1) ? f4.z : f4.x, mm, z0);
            z2 = fmaf((k & 1) ? f4.w : f4.y, mm, z2);
        }
    }

    out[b * 32 + p]      = z0;
    out[b * 32 + 16 + p] = z2;
}

extern "C" void kernel_launch(void* const* d_in, const int* in_sizes, int n_in,
                              void* d_out, int out_size, void* d_ws, size_t ws_size,
                              hipStream_t stream) {
    const float* x  = (const float*)d_in[0];
    const float* pr = (const float*)d_in[1];
    const float* pi = (const float*)d_in[2];
    const float* pe = (const float*)d_in[3];
    float* out = (float*)d_out;
    const int B = in_sizes[0] / 4;

    float2* WT = (float2*)d_ws;     // NQUAD*16 float4 = 17408 B

    build_W<<<NP, 256, 0, stream>>>(pr, pi, pe, WT);
    qnn_main<<<dim3((B * NP + 255) / 256), 256, 0, stream>>>(x, (const float4*)WT, out, B);
}

// Round 5
// 13.509 us; speedup vs baseline: 1.8665x; 1.3197x over previous
//
#include <hip/hip_runtime.h>
#include <math.h>

#define NP 16
#define NANG 28
#define NPAIR 136   // 16*17/2 upper-triangle pairs
#define KPAD 160    // padded K: 5 mfma k-steps of 32

typedef _Float16 h8 __attribute__((ext_vector_type(8)));
typedef float f4 __attribute__((ext_vector_type(4)));

// pair index k -> (i<=j), i-major upper triangle (matches build_W decode)
struct PairTab { int i[KPAD]; int j[KPAD]; };
constexpr PairTab make_tab() {
    PairTab t{};
    int k = 0;
    for (int a = 0; a < 16; ++a)
        for (int b = a; b < 16; ++b) { t.i[k] = a; t.j[k] = b; ++k; }
    for (; k < KPAD; ++k) { t.i[k] = 0; t.j[k] = 0; }
    return t;
}
constexpr PairTab TAB = make_tab();

// ================= build V_p = U_p * D via lane-shuffle evolution ============

template<int M>
__device__ __forceinline__ void g_ry(float& re, float& im, int idx, float c, float s) {
    float rep = __shfl_xor(re, M, 16);
    float imp = __shfl_xor(im, M, 16);
    float sgn = (idx & M) ? s : -s;
    re = fmaf(c, re, sgn * rep);
    im = fmaf(c, im, sgn * imp);
}

template<int M>  // RX / IsingXX: a' = c a - i s a_partner
__device__ __forceinline__ void g_rxlike(float& re, float& im, float c, float s) {
    float rep = __shfl_xor(re, M, 16);
    float imp = __shfl_xor(im, M, 16);
    re = fmaf(c, re,  s * imp);
    im = fmaf(c, im, -s * rep);
}

template<int CM, int TM>
__device__ __forceinline__ void g_crx(float& re, float& im, int idx, float c, float s) {
    float rep = __shfl_xor(re, TM, 16);
    float imp = __shfl_xor(im, TM, 16);
    float nre = fmaf(c, re,  s * imp);
    float nim = fmaf(c, im, -s * rep);
    re = (idx & CM) ? nre : re;
    im = (idx & CM) ? nim : im;
}

// One block per p: evolve V = U_p * D, reduce to quadratic forms
//   W0[i,j] = sum_q sign0(q) (Vr[q,i]Vr[q,j] + Vi[q,i]Vi[q,j])  (off-diag doubled)
// and store fp16 in MFMA B-frag layout: half index ((t*64 + g*16 + p)*8 + e)
// where pair k = t*32 + g*8 + e; k in [136,160) -> 0.
__global__ __launch_bounds__(256) void build_W(
    const float* __restrict__ p_rotation,
    const float* __restrict__ p_ising,
    const float* __restrict__ p_entangle,
    _Float16* __restrict__ W0h, _Float16* __restrict__ W2h)
{
    __shared__ float2 cs[NANG];
    __shared__ float2 V[256];   // V[q*16+col] = {re,im}
    const int p = blockIdx.x;
    const int tid = threadIdx.x;
    if (tid < NANG) {
        float ang;
        if (tid < 12)       ang = p_rotation[p * 12 + tid];
        else if (tid < 16)  ang = p_ising[p * 4 + (tid - 12)];
        else                ang = p_entangle[p * 12 + (tid - 16)];
        float s, c;
        __sincosf(0.5f * ang, &s, &c);
        cs[tid] = make_float2(c, s);
    }
    __syncthreads();

    const int idx = tid & 15;   // amplitude (row)
    const int col = tid >> 4;   // column of V = U*D
    const int ph = __popc(col) & 3;     // (-i)^popc phase of D
    const float dre = (ph == 0) ? 1.f : (ph == 2 ? -1.f : 0.f);
    const float dim = (ph == 1) ? -1.f : (ph == 3 ? 1.f : 0.f);
    float re = (idx == col) ? dre : 0.f;
    float im = (idx == col) ? dim : 0.f;

    float2 t;
    t = cs[0];  g_ry<8>(re, im, idx, t.x, t.y);
    t = cs[1];  g_ry<4>(re, im, idx, t.x, t.y);
    t = cs[2];  g_ry<2>(re, im, idx, t.x, t.y);
    t = cs[3];  g_ry<1>(re, im, idx, t.x, t.y);
    t = cs[12]; g_rxlike<12>(re, im, t.x, t.y);
    t = cs[13]; g_rxlike<3>(re, im, t.x, t.y);
    t = cs[4];  g_rxlike<8>(re, im, t.x, t.y);
    t = cs[5];  g_rxlike<4>(re, im, t.x, t.y);
    t = cs[6];  g_rxlike<2>(re, im, t.x, t.y);
    t = cs[7];  g_rxlike<1>(re, im, t.x, t.y);
    t = cs[14]; g_rxlike<6>(re, im, t.x, t.y);
    t = cs[15]; g_rxlike<9>(re, im, t.x, t.y);
    t = cs[8];  g_ry<8>(re, im, idx, t.x, t.y);
    t = cs[9];  g_ry<4>(re, im, idx, t.x, t.y);
    t = cs[10]; g_ry<2>(re, im, idx, t.x, t.y);
    t = cs[11]; g_ry<1>(re, im, idx, t.x, t.y);
    t = cs[16]; g_crx<8,4>(re, im, idx, t.x, t.y);
    t = cs[17]; g_crx<8,2>(re, im, idx, t.x, t.y);
    t = cs[18]; g_crx<8,1>(re, im, idx, t.x, t.y);
    t = cs[19]; g_crx<4,8>(re, im, idx, t.x, t.y);
    t = cs[20]; g_crx<4,2>(re, im, idx, t.x, t.y);
    t = cs[21]; g_crx<4,1>(re, im, idx, t.x, t.y);
    t = cs[22]; g_crx<2,8>(re, im, idx, t.x, t.y);
    t = cs[23]; g_crx<2,4>(re, im, idx, t.x, t.y);
    t = cs[24]; g_crx<2,1>(re, im, idx, t.x, t.y);
    t = cs[25]; g_crx<1,8>(re, im, idx, t.x, t.y);
    t = cs[26]; g_crx<1,4>(re, im, idx, t.x, t.y);
    t = cs[27]; g_crx<1,2>(re, im, idx, t.x, t.y);

    V[idx * 16 + col] = make_float2(re, im);
    __syncthreads();

    if (tid < KPAD) {
        float w0 = 0.f, w2 = 0.f;
        if (tid < NPAIR) {
            int i = 0, j = tid;             // decode pair index -> (i<=j)
            while (j >= 16 - i) { j -= 16 - i; ++i; }
            j += i;
            for (int q = 0; q < 16; ++q) {
                float2 a = V[q * 16 + i], b = V[q * 16 + j];
                float d = fmaf(a.x, b.x, a.y * b.y);
                w0 += (q & 8) ? -d : d;
                w2 += (q & 2) ? -d : d;
            }
            if (i != j) { w0 *= 2.f; w2 *= 2.f; }
        }
        const int tt = tid >> 5, r = tid & 31, g = r >> 3, e = r & 7;
        const int o = ((tt * 64 + g * 16 + p) << 3) + e;
        W0h[o] = (_Float16)w0;
        W2h[o] = (_Float16)w2;
    }
}

// ================= main: out = G * W via MFMA ===============================
// A = G [16 b-rows x K], B = W [K x 16 p-cols]; D col=lane&15, row=(lane>>4)*4+r

template<int G>
__device__ __forceinline__ void build_a(h8 af[5], const float m[16]) {
#pragma unroll
    for (int t = 0; t < 5; ++t) {
        h8 v = {};
#pragma unroll
        for (int e = 0; e < 8; ++e) {
            const int k = t * 32 + G * 8 + e;
            const float g = (k < NPAIR) ? m[TAB.i[k]] * m[TAB.j[k]] : 0.0f;
            v[e] = (_Float16)g;
        }
        af[t] = v;
    }
}

__global__ __launch_bounds__(256) void qnn_mfma(
    const float* __restrict__ x,
    const h8* __restrict__ W0f, const h8* __restrict__ W2f,
    float* __restrict__ out, int B)
{
    const int tid = threadIdx.x;
    const int lane = tid & 63;
    const int tile = (blockIdx.x << 2) + (tid >> 6);   // 16 b-rows per tile
    const int row = lane & 15, grp = lane >> 4;

    const float4 xv = reinterpret_cast<const float4*>(x)[tile * 16 + row];
    const float inv = rsqrtf(xv.x*xv.x + xv.y*xv.y + xv.z*xv.z + xv.w*xv.w);
    float c0,s0,c1,s1,c2,s2,c3,s3;
    __sincosf(0.5f * xv.x * inv, &s0, &c0);
    __sincosf(0.5f * xv.y * inv, &s1, &c1);
    __sincosf(0.5f * xv.z * inv, &s2, &c2);
    __sincosf(0.5f * xv.w * inv, &s3, &c3);

    float t01[4] = { c0*c1, c0*s1, s0*c1, s0*s1 };
    float t23[4] = { c2*c3, c2*s3, s2*c3, s2*s3 };
    float m[16];
#pragma unroll
    for (int i = 0; i < 16; ++i) m[i] = t01[i >> 2] * t23[i & 3];

    h8 af[5];
    if      (grp == 0) build_a<0>(af, m);
    else if (grp == 1) build_a<1>(af, m);
    else if (grp == 2) build_a<2>(af, m);
    else               build_a<3>(af, m);

    f4 acc0 = {0.f, 0.f, 0.f, 0.f};
    f4 acc1 = {0.f, 0.f, 0.f, 0.f};
#pragma unroll
    for (int t = 0; t < 5; ++t) {
        const h8 b0 = W0f[t * 64 + lane];
        const h8 b1 = W2f[t * 64 + lane];
        acc0 = __builtin_amdgcn_mfma_f32_16x16x32_f16(af[t], b0, acc0, 0, 0, 0);
        acc1 = __builtin_amdgcn_mfma_f32_16x16x32_f16(af[t], b1, acc1, 0, 0, 0);
    }

    const int brow = tile * 16 + grp * 4;
#pragma unroll
    for (int r = 0; r < 4; ++r) {
        out[(brow + r) * 32 + row]      = acc0[r];
        out[(brow + r) * 32 + 16 + row] = acc1[r];
    }
}

extern "C" void kernel_launch(void* const* d_in, const int* in_sizes, int n_in,
                              void* d_out, int out_size, void* d_ws, size_t ws_size,
                              hipStream_t stream) {
    const float* x  = (const float*)d_in[0];
    const float* pr = (const float*)d_in[1];
    const float* pi = (const float*)d_in[2];
    const float* pe = (const float*)d_in[3];
    float* out = (float*)d_out;
    const int B = in_sizes[0] / 4;

    _Float16* W0h = (_Float16*)d_ws;        // KPAD*16 halves = 5120 B
    _Float16* W2h = W0h + KPAD * NP;        // +5120 B

    build_W<<<NP, 256, 0, stream>>>(pr, pi, pe, W0h, W2h);
    qnn_mfma<<<B / 64, 256, 0, stream>>>(x, (const h8*)W0h, (const h8*)W2h, out, B);
}